// Round 5
// baseline (124.948 us; speedup 1.0000x reference)
//
#include <hip/hip_runtime.h>
#include <hip/hip_bf16.h>
#include <stdint.h>

#define NB 8
#define DIMG 2048
#define HWN 196
#define PN 1568
#define PPAD 1600
#define DMID 1024
#define NC 80
#define DWORD 300

typedef short bf16x8 __attribute__((ext_vector_type(8)));
typedef float f32x4 __attribute__((ext_vector_type(4)));

__device__ __forceinline__ unsigned short f2bf(float x) {
  union { float f; unsigned u; } c; c.f = x;
  unsigned r = c.u + 0x7FFFu + ((c.u >> 16) & 1u);
  return (unsigned short)(r >> 16);
}

// ---------------------------------------------------------------- transpose + W1 cvt (merged)
__global__ void k_tc(const float* __restrict__ img, float* __restrict__ fmap,
                     unsigned short* __restrict__ fmapH,
                     const float* __restrict__ W1, unsigned short* __restrict__ W1h) {
  __shared__ float tile[32][33];
  int bx = blockIdx.x;
  int tx = threadIdx.x, ty = threadIdx.y;
  if (bx < 3584) {
    int d0 = (bx & 63) * 32;
    int rem = bx >> 6;
    int h0 = (rem % 7) * 32, b = rem / 7;
    const float* src = img + (size_t)b * DIMG * HWN;
#pragma unroll
    for (int i = 0; i < 32; i += 8) {
      int hw = h0 + tx;
      tile[ty + i][tx] = (hw < HWN) ? src[(size_t)(d0 + ty + i) * HWN + hw] : 0.f;
    }
    __syncthreads();
#pragma unroll
    for (int i = 0; i < 32; i += 8) {
      int hw = h0 + ty + i;
      if (hw < HWN) {
        float v = tile[tx][ty + i];
        size_t o = (size_t)(b * HWN + hw) * DIMG + d0 + tx;
        fmap[o] = v;
        fmapH[o] = f2bf(v);
      }
    }
  } else {
    int tid = ty * 32 + tx;
    int i = ((bx - 3584) * 256 + tid) * 4;
    f32x4 v = *(const f32x4*)(W1 + i);
    ushort4 s;
    s.x = f2bf(v[0]); s.y = f2bf(v[1]); s.z = f2bf(v[2]); s.w = f2bf(v[3]);
    *(ushort4*)(W1h + i) = s;
  }
}

// ---------------------------------------------------------------- fwd + weff (coalesced, LDS-staged)
__global__ __launch_bounds__(256) void k_fwdweff(const float* __restrict__ word,
                                                 const float* __restrict__ W2,
                                                 float* __restrict__ fwd,
                                                 const float* __restrict__ Wa,
                                                 const float* __restrict__ W3,
                                                 float* __restrict__ partial) {
  __shared__ __align__(16) float w2s[64 * DWORD];   // 76.8 KB
  __shared__ __align__(16) float wds[16 * DWORD];   // 19.2 KB
  int bx = blockIdx.x, t = threadIdx.x;
  if (bx < 80) {
    int m0 = (bx & 15) * 64, c0 = (bx >> 4) * 16;
    const float SC = 2.8853900817779268f;  // 2*log2(e)
    for (int u = t; u < 64 * 75; u += 256) {
      int r = u / 75, q = u - r * 75;
      *(f32x4*)&w2s[r * DWORD + q * 4] =
          *(const f32x4*)(W2 + (size_t)(m0 + r) * DWORD + q * 4);
    }
    for (int u = t; u < 16 * 75; u += 256) {
      int r = u / 75, q = u - r * 75;
      f32x4 v = *(const f32x4*)(word + (size_t)(c0 + r) * DWORD + q * 4);
      *(f32x4*)&wds[r * DWORD + q * 4] = v * SC;
    }
    __syncthreads();
    int ci = t >> 4, mi = t & 15;
    f32x4 a0 = {0.f, 0.f, 0.f, 0.f}, a1 = a0, a2 = a0, a3 = a0;
    const float* wr = &wds[ci * DWORD];
    for (int q = 0; q < 75; ++q) {
      f32x4 wv = *(const f32x4*)&wr[q * 4];
      f32x4 b0 = *(const f32x4*)&w2s[(mi)*DWORD + q * 4];
      f32x4 b1 = *(const f32x4*)&w2s[(mi + 16) * DWORD + q * 4];
      f32x4 b2 = *(const f32x4*)&w2s[(mi + 32) * DWORD + q * 4];
      f32x4 b3 = *(const f32x4*)&w2s[(mi + 48) * DWORD + q * 4];
#pragma unroll
      for (int u = 0; u < 4; ++u) {
        a0[u] = fmaf(wv[u], b0[u], a0[u]);
        a1[u] = fmaf(wv[u], b1[u], a1[u]);
        a2[u] = fmaf(wv[u], b2[u], a2[u]);
        a3[u] = fmaf(wv[u], b3[u], a3[u]);
      }
    }
    float* dst = fwd + (size_t)(c0 + ci) * DMID + m0 + mi;
    dst[0]  = a0[0] + a0[1] + a0[2] + a0[3];
    dst[16] = a1[0] + a1[1] + a1[2] + a1[3];
    dst[32] = a2[0] + a2[1] + a2[2] + a2[3];
    dst[48] = a3[0] + a3[1] + a3[2] + a3[3];
  } else {
    int idx = bx - 80;
    int m = (idx & 3) * 256 + t;
    int n0 = (idx >> 2) * 64;
    float acc = 0.f;
    for (int n = n0; n < n0 + 64; ++n) acc = fmaf(Wa[n], W3[(size_t)n * DMID + m], acc);
    partial[(size_t)(idx >> 2) * DMID + m] = acc;
  }
}

// ---------------------------------------------------------------- GEMM: fwh[1600][1024] = fmapH x W1h^T
#define GLDS(g, l) \
  __builtin_amdgcn_global_load_lds((const __attribute__((address_space(1))) void*)(g), \
                                   (__attribute__((address_space(3))) void*)(l), 16, 0, 0)

__global__ __launch_bounds__(256) void k_gemm(const unsigned short* __restrict__ A,
                                              const unsigned short* __restrict__ Bw,
                                              float* __restrict__ C) {
  __shared__ __align__(16) unsigned short As[3][64 * 64];
  __shared__ __align__(16) unsigned short Bs[3][64 * 64];
  int m0 = blockIdx.x * 64, n0 = blockIdx.y * 64;
  int t = threadIdx.x;
  int w = t >> 6, l = t & 63;
  int wr = w >> 1, wc = w & 1;
  f32x4 zero = {0.f, 0.f, 0.f, 0.f};
  f32x4 acc00 = zero, acc01 = zero, acc10 = zero, acc11 = zero;

  int r0 = t >> 3, c0 = t & 7;
  int r1 = r0 + 32;
  const unsigned short* ga0 = A + (size_t)(m0 + r0) * 2048 + ((c0 ^ (r0 & 7)) << 3);
  const unsigned short* ga1 = A + (size_t)(m0 + r1) * 2048 + ((c0 ^ (r1 & 7)) << 3);
  const unsigned short* gb0 = Bw + (size_t)(n0 + r0) * 2048 + ((c0 ^ (r0 & 7)) << 3);
  const unsigned short* gb1 = Bw + (size_t)(n0 + r1) * 2048 + ((c0 ^ (r1 & 7)) << 3);

  int ra = wr * 32 + (l & 15);
  int rb = wc * 32 + (l & 15);
  int cc = l >> 4;
  int a_k0 = ra * 64 + (((cc) ^ (ra & 7)) << 3);
  int a_k1 = ra * 64 + (((cc + 4) ^ (ra & 7)) << 3);
  int b_k0 = rb * 64 + (((cc) ^ (rb & 7)) << 3);
  int b_k1 = rb * 64 + (((cc + 4) ^ (rb & 7)) << 3);

#define STAGE(bi, kk) do { \
    GLDS(ga0 + (kk), &As[bi][t * 8]); \
    GLDS(ga1 + (kk), &As[bi][t * 8 + 2048]); \
    GLDS(gb0 + (kk), &Bs[bi][t * 8]); \
    GLDS(gb1 + (kk), &Bs[bi][t * 8 + 2048]); \
  } while (0)

#define COMPUTE(bi) do { \
    const unsigned short* ap = As[bi]; \
    const unsigned short* bp = Bs[bi]; \
    bf16x8 A0 = *(const bf16x8*)(ap + a_k0); \
    bf16x8 A1 = *(const bf16x8*)(ap + a_k0 + 1024); \
    bf16x8 B0 = *(const bf16x8*)(bp + b_k0); \
    bf16x8 B1 = *(const bf16x8*)(bp + b_k0 + 1024); \
    acc00 = __builtin_amdgcn_mfma_f32_16x16x32_bf16(A0, B0, acc00, 0, 0, 0); \
    acc01 = __builtin_amdgcn_mfma_f32_16x16x32_bf16(A0, B1, acc01, 0, 0, 0); \
    acc10 = __builtin_amdgcn_mfma_f32_16x16x32_bf16(A1, B0, acc10, 0, 0, 0); \
    acc11 = __builtin_amdgcn_mfma_f32_16x16x32_bf16(A1, B1, acc11, 0, 0, 0); \
    bf16x8 A2 = *(const bf16x8*)(ap + a_k1); \
    bf16x8 A3 = *(const bf16x8*)(ap + a_k1 + 1024); \
    bf16x8 B2 = *(const bf16x8*)(bp + b_k1); \
    bf16x8 B3 = *(const bf16x8*)(bp + b_k1 + 1024); \
    acc00 = __builtin_amdgcn_mfma_f32_16x16x32_bf16(A2, B2, acc00, 0, 0, 0); \
    acc01 = __builtin_amdgcn_mfma_f32_16x16x32_bf16(A2, B3, acc01, 0, 0, 0); \
    acc10 = __builtin_amdgcn_mfma_f32_16x16x32_bf16(A3, B2, acc10, 0, 0, 0); \
    acc11 = __builtin_amdgcn_mfma_f32_16x16x32_bf16(A3, B3, acc11, 0, 0, 0); \
  } while (0)

  STAGE(0, 0);
  STAGE(1, 64);
  asm volatile("s_waitcnt vmcnt(4)" ::: "memory");
  __builtin_amdgcn_s_barrier();
  __builtin_amdgcn_sched_barrier(0);
  for (int kt = 0; kt < 32; ++kt) {
    int cur = kt % 3;
    if (kt < 30) STAGE((kt + 2) % 3, (kt + 2) * 64);
    COMPUTE(cur);
    if (kt < 30) {
      asm volatile("s_waitcnt vmcnt(4)" ::: "memory");
      __builtin_amdgcn_s_barrier();
      __builtin_amdgcn_sched_barrier(0);
    } else if (kt == 30) {
      asm volatile("s_waitcnt vmcnt(0)" ::: "memory");
      __builtin_amdgcn_s_barrier();
      __builtin_amdgcn_sched_barrier(0);
    }
  }
  int cr = (l >> 4) << 2, ccn = l & 15;
#pragma unroll
  for (int q = 0; q < 4; ++q) {
    C[(size_t)(m0 + wr * 32 + cr + q) * DMID + n0 + wc * 32 + ccn] = acc00[q];
    C[(size_t)(m0 + wr * 32 + cr + q) * DMID + n0 + wc * 32 + 16 + ccn] = acc01[q];
    C[(size_t)(m0 + wr * 32 + 16 + cr + q) * DMID + n0 + wc * 32 + ccn] = acc10[q];
    C[(size_t)(m0 + wr * 32 + 16 + cr + q) * DMID + n0 + wc * 32 + 16 + ccn] = acc11[q];
  }
#undef STAGE
#undef COMPUTE
}

// ---------------------------------------------------------------- coef logits, 2x2 register-blocked, m-split 4
// coefp[mz][p][c] = sum_{m in chunk mz} (-2 w_eff[m]) / (1 + e^{2 x_pm c})
#define MC 128
__global__ __launch_bounds__(256) void k_coef(const float* __restrict__ fwh,
                                              const float* __restrict__ fwd,
                                              const float* __restrict__ partial,
                                              float* __restrict__ coefp) {
  __shared__ __align__(16) float al[32][132];
  __shared__ __align__(16) float bl[32][132];
  __shared__ __align__(16) float wl[MC];
  int p0 = blockIdx.x * 32, c0 = blockIdx.y * 32, mz = blockIdx.z;
  int t = threadIdx.x;
  int pi = t >> 4, ci = t & 15;
  int pi2 = pi * 2, ci2 = ci * 2;
  float acc00 = 0.f, acc01 = 0.f, acc10 = 0.f, acc11 = 0.f;
  int srow = t >> 3, sch = t & 7;
  for (int mc = 0; mc < 256; mc += MC) {
    int mbase = mz * 256 + mc;
    __syncthreads();
    {
      const float* gA = fwh + (size_t)(p0 + srow) * DMID + mbase;
      const float* gB = fwd + (size_t)(c0 + srow) * DMID + mbase;
#pragma unroll
      for (int q = 0; q < 4; ++q) {
        int ch = (sch + q * 8) * 4;
        *(f32x4*)&al[srow][ch] = *(const f32x4*)&gA[ch];
        *(f32x4*)&bl[srow][ch] = *(const f32x4*)&gB[ch];
      }
      if (t < 32) {
        f32x4 v = {0.f, 0.f, 0.f, 0.f};
#pragma unroll
        for (int s = 0; s < 16; ++s)
          v += *(const f32x4*)(partial + (size_t)s * DMID + mbase + t * 4);
        *(f32x4*)&wl[t * 4] = v * -2.f;
      }
    }
    __syncthreads();
    for (int mm = 0; mm < MC; mm += 4) {
      f32x4 a0 = *(const f32x4*)&al[pi2][mm];
      f32x4 a1 = *(const f32x4*)&al[pi2 + 1][mm];
      f32x4 b0 = *(const f32x4*)&bl[ci2][mm];
      f32x4 b1 = *(const f32x4*)&bl[ci2 + 1][mm];
      f32x4 wv = *(const f32x4*)&wl[mm];
#pragma unroll
      for (int u = 0; u < 4; ++u) {
        float w = wv[u];
        float e00 = __builtin_amdgcn_exp2f(a0[u] * b0[u]);
        float e01 = __builtin_amdgcn_exp2f(a0[u] * b1[u]);
        float e10 = __builtin_amdgcn_exp2f(a1[u] * b0[u]);
        float e11 = __builtin_amdgcn_exp2f(a1[u] * b1[u]);
        acc00 = fmaf(w, __builtin_amdgcn_rcpf(1.f + e00), acc00);
        acc01 = fmaf(w, __builtin_amdgcn_rcpf(1.f + e01), acc01);
        acc10 = fmaf(w, __builtin_amdgcn_rcpf(1.f + e10), acc10);
        acc11 = fmaf(w, __builtin_amdgcn_rcpf(1.f + e11), acc11);
      }
    }
  }
  float* cp = coefp + (size_t)mz * (PN * NC);
  int p = p0 + pi2, c = c0 + ci2;
  if (c < NC) {
    cp[(size_t)p * NC + c] = acc00;
    cp[(size_t)(p + 1) * NC + c] = acc10;
  }
  if (c + 1 < NC) {
    cp[(size_t)p * NC + c + 1] = acc01;
    cp[(size_t)(p + 1) * NC + c + 1] = acc11;
  }
}

// ---------------------------------------------------------------- softmax + pooling (merged); sums 4 coef partials
__global__ __launch_bounds__(256) void k_pool(const float* __restrict__ coefp,
                                              const float* __restrict__ fmap,
                                              float* __restrict__ out) {
  __shared__ __align__(16) float wt[HWN][16];
  __shared__ float red[16][16];
  __shared__ float mxs[16], inv[16];
  int dc = blockIdx.x * 256, cg = blockIdx.y * 16, b = blockIdx.z;
  int t = threadIdx.x;
  for (int i = t; i < HWN * 16; i += 256) {
    int hw = i >> 4, j = i & 15;
    size_t o = (size_t)(b * HWN + hw) * NC + cg + j;
    wt[hw][j] = coefp[o] + coefp[o + PN * NC] + coefp[o + 2 * PN * NC] + coefp[o + 3 * PN * NC];
  }
  __syncthreads();
  int j = t & 15, g = t >> 4;
  float pm = -1e30f;
  for (int hw = g; hw < HWN; hw += 16) pm = fmaxf(pm, wt[hw][j]);
  red[g][j] = pm;
  __syncthreads();
  if (t < 16) {
    float m = red[0][t];
#pragma unroll
    for (int g2 = 1; g2 < 16; ++g2) m = fmaxf(m, red[g2][t]);
    mxs[t] = m;
  }
  __syncthreads();
  float mj = mxs[j], ps = 0.f;
  for (int hw = g; hw < HWN; hw += 16) {
    float e = __builtin_amdgcn_exp2f((wt[hw][j] - mj) * 1.4426950408889634f);
    wt[hw][j] = e;
    ps += e;
  }
  red[g][j] = ps;
  __syncthreads();
  if (t < 16) {
    float s = 0.f;
#pragma unroll
    for (int g2 = 0; g2 < 16; ++g2) s += red[g2][t];
    inv[t] = 1.f / s;
  }
  __syncthreads();
  float acc[16];
#pragma unroll
  for (int q = 0; q < 16; ++q) acc[q] = 0.f;
  const float* fp = fmap + (size_t)b * HWN * DIMG + dc + t;
  for (int hw = 0; hw < HWN; ++hw) {
    float v = fp[(size_t)hw * DIMG];
#pragma unroll
    for (int q = 0; q < 16; ++q) acc[q] = fmaf(wt[hw][q], v, acc[q]);
  }
#pragma unroll
  for (int q = 0; q < 16; ++q)
    out[((size_t)b * NC + cg + q) * DIMG + dc + t] = acc[q] * inv[q];
}

// ----------------------------------------------------------------
extern "C" void kernel_launch(void* const* d_in, const int* in_sizes, int n_in,
                              void* d_out, int out_size, void* d_ws, size_t ws_size,
                              hipStream_t stream) {
  const float* img  = (const float*)d_in[1];
  const float* word = (const float*)d_in[2];
  const float* W1   = (const float*)d_in[3];
  const float* W2   = (const float*)d_in[4];
  const float* W3   = (const float*)d_in[5];
  const float* Wa   = (const float*)d_in[7];
  // b3 (d_in[6]) and ba (d_in[8]) are softmax-shift-invariant -> dropped.
  float* out = (float*)d_out;
  char* ws = (char*)d_ws;

  float*          fmap    = (float*)(ws + 0);                  // 12,845,056
  unsigned short* fmapH   = (unsigned short*)(ws + 12845056);  //  6,553,600
  unsigned short* W1h     = (unsigned short*)(ws + 19398656);  //  4,194,304
  float*          fwh     = (float*)(ws + 23592960);           //  6,553,600
  float*          fwd     = (float*)(ws + 30146560);           //  96*1024*4 = 393,216 (rows 80-95 stale, finite)
  float*          partial = (float*)(ws + 30539776);           //     65,536
  float*          coefp   = (float*)(ws + 30605312);           // 4*1568*80*4 = 2,007,040

  hipLaunchKernelGGL(k_tc, dim3(5632), dim3(32, 8), 0, stream, img, fmap, fmapH, W1, W1h);
  hipLaunchKernelGGL(k_fwdweff, dim3(144), dim3(256), 0, stream,
                     word, W2, fwd, Wa, W3, partial);
  hipLaunchKernelGGL(k_gemm, dim3(25, 16), dim3(256), 0, stream, fmapH, W1h, fwh);
  hipLaunchKernelGGL(k_coef, dim3(49, 3, 4), dim3(256), 0, stream, fwh, fwd, partial, coefp);
  hipLaunchKernelGGL(k_pool, dim3(8, 5, 8), dim3(256), 0, stream, coefp, fmap, out);
  (void)in_sizes; (void)n_in; (void)out_size; (void)ws_size;
}